// Round 2
// baseline (887.591 us; speedup 1.0000x reference)
//
#include <hip/hip_runtime.h>

#define NPTS  65536
#define KNB   32
#define KPn   15
#define CIN   64
#define COUT  128
#define MPTS  16      // points per block
#define THREADS 256

__global__ __launch_bounds__(THREADS, 2) void kpconv_kernel(
    const float* __restrict__ pos,       // [N,3] f32
    const float* __restrict__ feats,     // [N,64] f32
    const float* __restrict__ kpts,      // [15,3] f32
    const float* __restrict__ weights,   // [15,64,128] f32
    const int*   __restrict__ neighbors, // [N,32] int32
    float*       __restrict__ out)       // [N,128] f32
{
    __shared__ float kpf[3][KPn];            // [xyz][k]
    __shared__ float infl[KPn][KNB + 1];
    __shared__ int   nbidx[KNB];
    __shared__ int   jact[KNB];
    __shared__ float nf[KNB][CIN];           // gathered neighbor feats
    __shared__ float wl[MPTS][KPn * CIN];    // weighted [16][960], 61.4 KB

    const int tid = threadIdx.x;
    const int n0  = blockIdx.x * MPTS;

    if (tid < KPn * 3) kpf[tid % 3][tid / 3] = kpts[tid];
    __syncthreads();

    for (int p = 0; p < MPTS; ++p) {
        const int n = n0 + p;
        // ---- per-neighbor influence + active flag (threads 0..31) ----
        if (tid < KNB) {
            const int j  = tid;
            const int nb = neighbors[n * KNB + j];
            nbidx[j] = nb;
            const float rx = pos[nb * 3 + 0] - pos[n * 3 + 0];
            const float ry = pos[nb * 3 + 1] - pos[n * 3 + 1];
            const float rz = pos[nb * 3 + 2] - pos[n * 3 + 2];
            int any = 0;
            #pragma unroll
            for (int k = 0; k < KPn; ++k) {
                const float dx = rx - kpf[0][k];
                const float dy = ry - kpf[1][k];
                const float dz = rz - kpf[2][k];
                const float dist = sqrtf(dx * dx + dy * dy + dz * dz);
                float w = 1.0f - dist * 10.0f;   // 1/SIGMA = 10
                w = fmaxf(w, 0.0f);
                infl[k][j] = w;
                any |= (w > 0.0f) ? 1 : 0;
            }
            jact[j] = any;
        }
        __syncthreads();

        // ---- gather neighbor feats for ACTIVE neighbors only ----
        for (int i = tid; i < KNB * (CIN / 4); i += THREADS) {
            const int j = i >> 4;                 // 16 float4s per row
            if (jact[j]) {
                const int c4 = (i & 15) * 4;
                const float4 f = *(const float4*)(feats + (size_t)nbidx[j] * CIN + c4);
                *(float4*)&nf[j][c4] = f;
            }
        }
        __syncthreads();

        // ---- wl[p][k*64+c] = sum_j infl[k][j] * nf[j][c]  (skip inactive) ----
        if (tid < KPn * 16) {
            const int k = tid >> 4;
            const int c = (tid & 15) * 4;
            float4 acc = make_float4(0.f, 0.f, 0.f, 0.f);
            for (int j = 0; j < KNB; ++j) {
                if (jact[j]) {
                    const float w = infl[k][j];
                    const float4 f = *(const float4*)&nf[j][c];
                    acc.x += w * f.x; acc.y += w * f.y;
                    acc.z += w * f.z; acc.w += w * f.w;
                }
            }
            *(float4*)&wl[p][k * CIN + c] = acc;
        }
        __syncthreads();
    }

    // ---- stage 2: out[16][128] = wl[16][960] @ W[960][128] ----
    // thread (q = tid&3, g = tid>>2): cols {2g,2g+1}, kc-chunk [q*240, q*240+240)
    // each weight element loaded exactly once per block; reduce over q via shfl
    {
        const int q   = tid & 3;
        const int g   = tid >> 2;
        const int c0  = 2 * g;
        const int kc0 = q * 240;
        float acc0[MPTS];   // col c0
        float acc1[MPTS];   // col c0+1
        #pragma unroll
        for (int r = 0; r < MPTS; ++r) { acc0[r] = 0.f; acc1[r] = 0.f; }

        for (int kc = kc0; kc < kc0 + 240; kc += 4) {
            float2 w0 = *(const float2*)(weights + (size_t)(kc + 0) * COUT + c0);
            float2 w1 = *(const float2*)(weights + (size_t)(kc + 1) * COUT + c0);
            float2 w2 = *(const float2*)(weights + (size_t)(kc + 2) * COUT + c0);
            float2 w3 = *(const float2*)(weights + (size_t)(kc + 3) * COUT + c0);
            #pragma unroll
            for (int r = 0; r < MPTS; ++r) {
                const float4 a = *(const float4*)&wl[r][kc];
                acc0[r] += a.x * w0.x + a.y * w1.x + a.z * w2.x + a.w * w3.x;
                acc1[r] += a.x * w0.y + a.y * w1.y + a.z * w2.y + a.w * w3.y;
            }
        }

        // reduce the 4 q-lanes (adjacent lanes in the same wave)
        #pragma unroll
        for (int r = 0; r < MPTS; ++r) {
            acc0[r] += __shfl_down(acc0[r], 1);
            acc0[r] += __shfl_down(acc0[r], 2);
            acc1[r] += __shfl_down(acc1[r], 1);
            acc1[r] += __shfl_down(acc1[r], 2);
        }

        if (q == 0) {
            #pragma unroll
            for (int r = 0; r < MPTS; ++r) {
                float2 o; o.x = acc0[r]; o.y = acc1[r];
                *(float2*)(out + (size_t)(n0 + r) * COUT + c0) = o;
            }
        }
    }
}

extern "C" void kernel_launch(void* const* d_in, const int* in_sizes, int n_in,
                              void* d_out, int out_size, void* d_ws, size_t ws_size,
                              hipStream_t stream) {
    const float* pos       = (const float*)d_in[0];
    const float* feats     = (const float*)d_in[1];
    const float* kpts      = (const float*)d_in[2];
    const float* weights   = (const float*)d_in[3];
    const int*   neighbors = (const int*)d_in[4];
    float*       out       = (float*)d_out;

    const int grid = NPTS / MPTS;  // 4096 blocks
    kpconv_kernel<<<grid, THREADS, 0, stream>>>(pos, feats, kpts, weights, neighbors, out);
}

// Round 3
// 255.144 us; speedup vs baseline: 3.4788x; 3.4788x over previous
//
#include <hip/hip_runtime.h>

#define NPTS  65536
#define KNB   32
#define KPn   15
#define CIN   64
#define COUT  128
#define MPTS  16            // points per block
#define THREADS 256
#define WLD   972           // wl row stride in floats (960 + 12 pad: 2-way-bank-free)
#define MAXE  1536          // active-entry list capacity

typedef __attribute__((ext_vector_type(8))) short short8;
typedef __attribute__((ext_vector_type(4))) float f32x4;

__device__ __forceinline__ unsigned int f2bf(float f) {
    union { float f; unsigned int i; } v; v.f = f;
    return (v.i + 0x7fffu + ((v.i >> 16) & 1u)) >> 16;   // RNE
}

// ---- prep: weights [15*64=960][128] f32  ->  wT [128][960] bf16 ----
__global__ void wtrans_kernel(const float* __restrict__ w,
                              unsigned short* __restrict__ wT) {
    const int i = blockIdx.x * 256 + threadIdx.x;
    if (i < KPn * CIN * COUT) {
        const int k = i >> 7;        // 0..959
        const int n = i & 127;       // 0..127
        wT[n * 960 + k] = (unsigned short)f2bf(w[i]);
    }
}

__global__ __launch_bounds__(THREADS, 2) void kpconv_kernel(
    const float* __restrict__ pos,       // [N,3] f32
    const float* __restrict__ feats,     // [N,64] f32
    const float* __restrict__ kpts,      // [15,3] f32
    const unsigned short* __restrict__ wT, // [128][960] bf16 (from prep)
    const int*   __restrict__ neighbors, // [N,32] int32
    float*       __restrict__ out)       // [N,128] f32
{
    __shared__ float wl[MPTS * WLD];     // 62208 B, f32 accumulators
    __shared__ int   nbidx[MPTS * KNB];  // 2 KB
    __shared__ int   eid[MAXE];          // 6 KB  (slot<<4 | k)
    __shared__ float eval_[MAXE];        // 6 KB
    __shared__ float cposf[MPTS * 3];    // 192 B
    __shared__ float kpfl[KPn * 3];      // 180 B
    __shared__ int   ecount;

    const int tid = threadIdx.x;
    const int n0  = blockIdx.x * MPTS;

    // ---- init: zero wl, load center pos + kernel points ----
    {
        float4 z = make_float4(0.f, 0.f, 0.f, 0.f);
        for (int i = tid; i < MPTS * WLD / 4; i += THREADS)
            ((float4*)wl)[i] = z;
        if (tid < MPTS * 3) cposf[tid] = pos[(size_t)n0 * 3 + tid];
        if (tid < KPn * 3)  kpfl[tid]  = kpts[tid];
        if (tid == 0) ecount = 0;
    }
    __syncthreads();

    // ---- stage 1a: influence for all 512 (p,j) slots; push active entries ----
    for (int s = tid; s < MPTS * KNB; s += THREADS) {
        const int p  = s >> 5;
        const int nb = neighbors[(size_t)n0 * KNB + s];
        nbidx[s] = nb;
        const float rx = pos[(size_t)nb * 3 + 0] - cposf[p * 3 + 0];
        const float ry = pos[(size_t)nb * 3 + 1] - cposf[p * 3 + 1];
        const float rz = pos[(size_t)nb * 3 + 2] - cposf[p * 3 + 2];
        #pragma unroll
        for (int k = 0; k < KPn; ++k) {
            const float dx = rx - kpfl[k * 3 + 0];
            const float dy = ry - kpfl[k * 3 + 1];
            const float dz = rz - kpfl[k * 3 + 2];
            const float d2 = dx * dx + dy * dy + dz * dz;
            if (d2 < 0.01f) {                       // dist < sigma  =>  infl > 0
                const float w = 1.0f - 10.0f * sqrtf(d2);
                const int idx = atomicAdd(&ecount, 1);
                if (idx < MAXE) { eid[idx] = (s << 4) | k; eval_[idx] = w; }
            }
        }
    }
    __syncthreads();

    // ---- stage 1b: scatter-accumulate infl * feats into wl (f32 LDS atomics) ----
    {
        const int E = min(ecount, MAXE);
        const int tot = E * 16;                      // 16 float4-chunks of Cin=64
        for (int i = tid; i < tot; i += THREADS) {
            const int e  = i >> 4;
            const int c4 = (i & 15) << 2;
            const int id = eid[e];
            const float w = eval_[e];
            const int s = id >> 4, k = id & 15;
            const int p = s >> 5;
            const float4 f = *(const float4*)(feats + (size_t)nbidx[s] * CIN + c4);
            float* dst = &wl[p * WLD + k * CIN + c4];
            atomicAdd(dst + 0, w * f.x);
            atomicAdd(dst + 1, w * f.y);
            atomicAdd(dst + 2, w * f.z);
            atomicAdd(dst + 3, w * f.w);
        }
    }
    __syncthreads();

    // ---- stage 2: out[16][128] = wl[16][960] @ W[960][128] via MFMA bf16 ----
    // wave w handles col tiles [w*32, w*32+16) and [w*32+16, w*32+32)
    {
        const int wave = tid >> 6;
        const int lane = tid & 63;
        const int m    = lane & 15;       // A row (point), B col (n within tile)
        const int q    = lane >> 4;       // quad: k = q*8 + j
        const int nb0  = wave * 32;

        f32x4 acc0 = {0.f, 0.f, 0.f, 0.f};
        f32x4 acc1 = {0.f, 0.f, 0.f, 0.f};

        const float* ap = &wl[m * WLD + q * 8];
        const unsigned short* bp0 = wT + (size_t)(nb0 + m) * 960 + q * 8;
        const unsigned short* bp1 = bp0 + 16 * 960;

        for (int ks = 0; ks < 30; ++ks, ap += 32, bp0 += 32, bp1 += 32) {
            const float4 alo = *(const float4*)(ap);
            const float4 ahi = *(const float4*)(ap + 4);
            short8 a;
            a[0] = (short)f2bf(alo.x); a[1] = (short)f2bf(alo.y);
            a[2] = (short)f2bf(alo.z); a[3] = (short)f2bf(alo.w);
            a[4] = (short)f2bf(ahi.x); a[5] = (short)f2bf(ahi.y);
            a[6] = (short)f2bf(ahi.z); a[7] = (short)f2bf(ahi.w);
            const short8 b0 = *(const short8*)(bp0);
            const short8 b1 = *(const short8*)(bp1);
            acc0 = __builtin_amdgcn_mfma_f32_16x16x32_bf16(a, b0, acc0, 0, 0, 0);
            acc1 = __builtin_amdgcn_mfma_f32_16x16x32_bf16(a, b1, acc1, 0, 0, 0);
        }

        // C/D layout: col = lane&15, row = q*4 + reg
        #pragma unroll
        for (int r = 0; r < 4; ++r) {
            const size_t row = (size_t)(n0 + q * 4 + r) * COUT;
            out[row + nb0 + m]      = acc0[r];
            out[row + nb0 + 16 + m] = acc1[r];
        }
    }
}

extern "C" void kernel_launch(void* const* d_in, const int* in_sizes, int n_in,
                              void* d_out, int out_size, void* d_ws, size_t ws_size,
                              hipStream_t stream) {
    const float* pos       = (const float*)d_in[0];
    const float* feats     = (const float*)d_in[1];
    const float* kpts      = (const float*)d_in[2];
    const float* weights   = (const float*)d_in[3];
    const int*   neighbors = (const int*)d_in[4];
    float*       out       = (float*)d_out;
    unsigned short* wT     = (unsigned short*)d_ws;   // 128*960*2 = 245760 B

    wtrans_kernel<<<(KPn * CIN * COUT + 255) / 256, 256, 0, stream>>>(weights, wT);
    kpconv_kernel<<<NPTS / MPTS, THREADS, 0, stream>>>(pos, feats, kpts, wT, neighbors, out);
}

// Round 4
// 201.492 us; speedup vs baseline: 4.4051x; 1.2663x over previous
//
#include <hip/hip_runtime.h>

#define NPTS  65536
#define KNB   32
#define KPn   15
#define CIN   64
#define COUT  128
#define MPTS  16            // points per block (MFMA M)
#define THREADS 256
#define WLD   972           // wl row stride in floats (960 + 12 pad)
#define MAXE  768           // active-entry list capacity (~31 expected)
#define NTILE 8             // 128 cols / 16
#define KSTEPS 30           // 960 / 32

typedef __attribute__((ext_vector_type(8))) short short8;
typedef __attribute__((ext_vector_type(4))) float f32x4;

__device__ __forceinline__ unsigned int f2bf(float f) {
    union { float f; unsigned int i; } v; v.f = f;
    return (v.i + 0x7fffu + ((v.i >> 16) & 1u)) >> 16;   // RNE
}

// ---- prep: weights [960][128] f32 -> wTf in MFMA B-fragment order ----
// wTf[((t*30 + ks)*64 + lane)*8 + j] = W[ks*32 + (lane>>4)*8 + j][t*16 + (lane&15)]
__global__ void wtrans_kernel(const float* __restrict__ w,
                              unsigned short* __restrict__ wTf) {
    const int i = blockIdx.x * 256 + threadIdx.x;   // (t,ks,lane) id
    if (i < NTILE * KSTEPS * 64) {
        const int lane = i & 63;
        const int ks   = (i >> 6) % KSTEPS;
        const int t    = i / (64 * KSTEPS);
        const int kbase = ks * 32 + (lane >> 4) * 8;
        const int n     = t * 16 + (lane & 15);
        unsigned short frag[8];
        #pragma unroll
        for (int j = 0; j < 8; ++j)
            frag[j] = (unsigned short)f2bf(w[(size_t)(kbase + j) * COUT + n]);
        *(short8*)(wTf + (size_t)i * 8) = *(short8*)frag;
    }
}

__global__ __launch_bounds__(THREADS, 2) void kpconv_kernel(
    const float* __restrict__ pos,         // [N,3] f32
    const float* __restrict__ feats,       // [N,64] f32
    const float* __restrict__ kpts,        // [15,3] f32
    const unsigned short* __restrict__ wTf,// fragment-packed bf16 weights
    const int*   __restrict__ neighbors,   // [N,32] int32
    float*       __restrict__ out)         // [N,128] f32
{
    __shared__ float wl[MPTS * WLD];     // 62208 B, f32 accumulators
    __shared__ int   nbidx[MPTS * KNB];  // 2 KB
    __shared__ int   eid[MAXE];          // 3 KB  (slot<<4 | k)
    __shared__ float eval_[MAXE];        // 3 KB
    __shared__ float cposf[MPTS * 3];
    __shared__ float kpfl[KPn * 3];
    __shared__ int   ecount;

    const int tid = threadIdx.x;
    const int n0  = blockIdx.x * MPTS;

    // ---- init ----
    {
        float4 z = make_float4(0.f, 0.f, 0.f, 0.f);
        for (int i = tid; i < MPTS * WLD / 4; i += THREADS)
            ((float4*)wl)[i] = z;
        if (tid < MPTS * 3) cposf[tid] = pos[(size_t)n0 * 3 + tid];
        if (tid < KPn * 3)  kpfl[tid]  = kpts[tid];
        if (tid == 0) ecount = 0;
    }
    __syncthreads();

    // ---- stage 1a: influences for all 512 (p,j) slots; push active entries ----
    for (int s = tid; s < MPTS * KNB; s += THREADS) {
        const int p  = s >> 5;
        const int nb = neighbors[(size_t)n0 * KNB + s];
        nbidx[s] = nb;
        const float rx = pos[(size_t)nb * 3 + 0] - cposf[p * 3 + 0];
        const float ry = pos[(size_t)nb * 3 + 1] - cposf[p * 3 + 1];
        const float rz = pos[(size_t)nb * 3 + 2] - cposf[p * 3 + 2];
        #pragma unroll
        for (int k = 0; k < KPn; ++k) {
            const float dx = rx - kpfl[k * 3 + 0];
            const float dy = ry - kpfl[k * 3 + 1];
            const float dz = rz - kpfl[k * 3 + 2];
            const float d2 = dx * dx + dy * dy + dz * dz;
            if (d2 < 0.01f) {                       // dist < sigma
                const float w = 1.0f - 10.0f * sqrtf(d2);
                const int idx = atomicAdd(&ecount, 1);
                if (idx < MAXE) { eid[idx] = (s << 4) | k; eval_[idx] = w; }
            }
        }
    }
    __syncthreads();

    // ---- stage 1b: scatter-accumulate infl * feats into wl ----
    {
        const int E = min(ecount, MAXE);
        const int tot = E * 16;
        for (int i = tid; i < tot; i += THREADS) {
            const int e  = i >> 4;
            const int c4 = (i & 15) << 2;
            const int id = eid[e];
            const float w = eval_[e];
            const int s = id >> 4, k = id & 15;
            const int p = s >> 5;
            const float4 f = *(const float4*)(feats + (size_t)nbidx[s] * CIN + c4);
            float* dst = &wl[p * WLD + k * CIN + c4];
            atomicAdd(dst + 0, w * f.x);
            atomicAdd(dst + 1, w * f.y);
            atomicAdd(dst + 2, w * f.z);
            atomicAdd(dst + 3, w * f.w);
        }
    }
    __syncthreads();

    // ---- stage 2: out[16][128] = wl[16][960] @ W[960][128] via MFMA bf16 ----
    {
        const int wave = tid >> 6;
        const int lane = tid & 63;
        const int m    = lane & 15;
        const int q    = lane >> 4;

        f32x4 acc0 = {0.f, 0.f, 0.f, 0.f};
        f32x4 acc1 = {0.f, 0.f, 0.f, 0.f};

        const float* ap = &wl[m * WLD + q * 8];
        // fragment-packed B: tiles (2*wave) and (2*wave+1), coalesced short8/lane
        const short8* bp0 = (const short8*)wTf + (size_t)(2 * wave) * KSTEPS * 64 + lane;
        const short8* bp1 = bp0 + (size_t)KSTEPS * 64;

        #pragma unroll 2
        for (int ks = 0; ks < KSTEPS; ++ks, ap += 32) {
            const float4 alo = *(const float4*)(ap);
            const float4 ahi = *(const float4*)(ap + 4);
            short8 a;
            a[0] = (short)f2bf(alo.x); a[1] = (short)f2bf(alo.y);
            a[2] = (short)f2bf(alo.z); a[3] = (short)f2bf(alo.w);
            a[4] = (short)f2bf(ahi.x); a[5] = (short)f2bf(ahi.y);
            a[6] = (short)f2bf(ahi.z); a[7] = (short)f2bf(ahi.w);
            const short8 b0 = bp0[ks * 64];
            const short8 b1 = bp1[ks * 64];
            acc0 = __builtin_amdgcn_mfma_f32_16x16x32_bf16(a, b0, acc0, 0, 0, 0);
            acc1 = __builtin_amdgcn_mfma_f32_16x16x32_bf16(a, b1, acc1, 0, 0, 0);
        }

        // C/D layout: col = lane&15, row = q*4 + reg
        const int nb0 = wave * 32;
        #pragma unroll
        for (int r = 0; r < 4; ++r) {
            const size_t row = (size_t)(n0 + q * 4 + r) * COUT;
            out[row + nb0 + m]      = acc0[r];
            out[row + nb0 + 16 + m] = acc1[r];
        }
    }
}

extern "C" void kernel_launch(void* const* d_in, const int* in_sizes, int n_in,
                              void* d_out, int out_size, void* d_ws, size_t ws_size,
                              hipStream_t stream) {
    const float* pos       = (const float*)d_in[0];
    const float* feats     = (const float*)d_in[1];
    const float* kpts      = (const float*)d_in[2];
    const float* weights   = (const float*)d_in[3];
    const int*   neighbors = (const int*)d_in[4];
    float*       out       = (float*)d_out;
    unsigned short* wTf    = (unsigned short*)d_ws;   // 8*30*64*8*2 = 245760 B

    wtrans_kernel<<<(NTILE * KSTEPS * 64 + 255) / 256, 256, 0, stream>>>(weights, wTf);
    kpconv_kernel<<<NPTS / MPTS, THREADS, 0, stream>>>(pos, feats, kpts, wTf, neighbors, out);
}